// Round 2
// baseline (2291.771 us; speedup 1.0000x reference)
//
#include <hip/hip_runtime.h>
#include <hip/hip_bf16.h>
#include <float.h>

#define NN 200000
#define NE 400000
#define NG 4096
#define FIN 77
#define DD 128
#define BN_EPS 1e-5f

// ---------- dtype detection (int64 vs int32 index arrays) ----------
// Sample ODD word indices near the END of each array. For an int64 array of
// nonneg values < 2^31, every odd word (high half) is 0. For int32:
//  - batch is sorted ascending to ~4095, so end words are nonzero.
//  - edge_index end words are random node ids (nonzero w.h.p.).
__global__ void detect_kernel(const unsigned* eidx, const unsigned* batch, int* flags) {
    if (threadIdx.x == 0 && blockIdx.x == 0) {
        int e64 = 1, b64 = 1;
        // last word index of eidx (2*NE words if int32, 4*NE if int64; use 2*NE-1 — in bounds either way)
        for (int i = 0; i < 16; i++) {
            unsigned we = eidx[2 * NE - 1 - 2 * i];   // odd indices
            if (we != 0u) e64 = 0;
        }
        for (int i = 0; i < 16; i++) {
            unsigned wb = batch[NN - 1 - 2 * i];      // NN-1 = 199999 is odd
            if (wb != 0u) b64 = 0;
        }
        flags[0] = e64;
        flags[1] = b64;
    }
}

__device__ __forceinline__ int load_idx(const void* p, int is64, long long i) {
    return is64 ? (int)((const long long*)p)[i] : ((const int*)p)[i];
}

// ---------- graph start offsets via binary search (batch is sorted) ----------
__global__ void graph_starts_kernel(const void* batch, const int* flags, int* start) {
    int g = blockIdx.x * blockDim.x + threadIdx.x;
    if (g > NG) return;
    int is64 = flags[1];
    int lo = 0, hi = NN;
    while (lo < hi) {
        int mid = (lo + hi) >> 1;
        int v = load_idx(batch, is64, mid);
        if (v < g) lo = mid + 1; else hi = mid;
    }
    start[g] = lo;
}

// ---------- edge scatter-add: agg[dst] += h[src] ----------
template <int K>
__global__ void scatter_add_kernel(const float* __restrict__ h, const void* eidx,
                                   const int* __restrict__ flags, float* __restrict__ agg) {
    long long t = (long long)blockIdx.x * blockDim.x + threadIdx.x;
    if (t >= (long long)NE * K) return;
    int e = (int)(t / K);
    int c = (int)(t % K);
    int is64 = flags[0];
    int src = load_idx(eidx, is64, e);
    int dst = load_idx(eidx, is64, (long long)NE + e);
    atomicAdd(&agg[(long long)dst * DD + c], h[(long long)src * K + c]);
}

// ---------- fused GEMM: C = [relu]((X1 [+ X2]) @ W + bias), X:[N,K] W:[K,128] ----------
template <bool ADD2, bool RELU>
__global__ __launch_bounds__(256) void gemm_kernel(
    const float* __restrict__ X1, const float* __restrict__ X2,
    const float* __restrict__ W, const float* __restrict__ bias,
    float* __restrict__ C, int K)
{
    __shared__ float xs[64][33];     // +1 pad
    __shared__ float ws[32][128];
    int tid = threadIdx.x;
    int tx = tid & 15;               // col group (8 cols)
    int ty = tid >> 4;               // row group (4 rows)
    long long rowBase = (long long)blockIdx.x * 64;

    float acc[4][8];
#pragma unroll
    for (int i = 0; i < 4; i++)
#pragma unroll
        for (int j = 0; j < 8; j++) acc[i][j] = 0.f;

    for (int kt = 0; kt < K; kt += 32) {
        // stage X tile [64 x 32]
#pragma unroll
        for (int i = 0; i < 8; i++) {
            int idx = tid + i * 256;
            int r = idx >> 5, c = idx & 31;
            int k = kt + c;
            float v = 0.f;
            if (k < K) {
                long long row = rowBase + r;
                v = X1[row * K + k];
                if (ADD2) v += X2[row * DD + k];
            }
            xs[r][c] = v;
        }
        // stage W tile [32 x 128]
#pragma unroll
        for (int i = 0; i < 16; i++) {
            int idx = tid + i * 256;
            int r = idx >> 7, c = idx & 127;
            int k = kt + r;
            ws[r][c] = (k < K) ? W[(long long)k * DD + c] : 0.f;
        }
        __syncthreads();
#pragma unroll
        for (int kk = 0; kk < 32; kk++) {
            float4 b0 = *(const float4*)(&ws[kk][tx * 8]);
            float4 b1 = *(const float4*)(&ws[kk][tx * 8 + 4]);
#pragma unroll
            for (int i = 0; i < 4; i++) {
                float a = xs[ty * 4 + i][kk];
                acc[i][0] += a * b0.x; acc[i][1] += a * b0.y;
                acc[i][2] += a * b0.z; acc[i][3] += a * b0.w;
                acc[i][4] += a * b1.x; acc[i][5] += a * b1.y;
                acc[i][6] += a * b1.z; acc[i][7] += a * b1.w;
            }
        }
        __syncthreads();
    }

    float bs[8];
#pragma unroll
    for (int j = 0; j < 8; j++) bs[j] = bias[tx * 8 + j];
#pragma unroll
    for (int i = 0; i < 4; i++) {
        long long row = rowBase + ty * 4 + i;
        float4 o0, o1;
        o0.x = acc[i][0] + bs[0]; o0.y = acc[i][1] + bs[1];
        o0.z = acc[i][2] + bs[2]; o0.w = acc[i][3] + bs[3];
        o1.x = acc[i][4] + bs[4]; o1.y = acc[i][5] + bs[5];
        o1.z = acc[i][6] + bs[6]; o1.w = acc[i][7] + bs[7];
        if (RELU) {
            o0.x = fmaxf(o0.x, 0.f); o0.y = fmaxf(o0.y, 0.f);
            o0.z = fmaxf(o0.z, 0.f); o0.w = fmaxf(o0.w, 0.f);
            o1.x = fmaxf(o1.x, 0.f); o1.y = fmaxf(o1.y, 0.f);
            o1.z = fmaxf(o1.z, 0.f); o1.w = fmaxf(o1.w, 0.f);
        }
        *(float4*)(&C[row * DD + tx * 8]) = o0;
        *(float4*)(&C[row * DD + tx * 8 + 4]) = o1;
    }
}

// ---------- BN: column sums / sumsq ----------
__global__ void bn_reduce_kernel(const float* __restrict__ h, float* __restrict__ sums) {
    int c = threadIdx.x; // 128
    float s = 0.f, q = 0.f;
    for (long long r = blockIdx.x; r < NN; r += gridDim.x) {
        float v = h[r * DD + c];
        s += v; q += v * v;
    }
    atomicAdd(&sums[c], s);
    atomicAdd(&sums[DD + c], q);
}

__global__ void bn_finalize_kernel(const float* __restrict__ sums,
                                   const float* __restrict__ gamma,
                                   const float* __restrict__ beta,
                                   float* __restrict__ ss) {
    int c = threadIdx.x;
    float mu = sums[c] / (float)NN;
    float var = sums[DD + c] / (float)NN - mu * mu;
    float sc = gamma[c] * rsqrtf(var + BN_EPS);
    ss[c] = sc;
    ss[DD + c] = beta[c] - mu * sc;
}

__global__ void bn_apply_kernel(float* __restrict__ h, const float* __restrict__ ss) {
    __shared__ float sc[DD], sh[DD];
    int tid = threadIdx.x;
    if (tid < DD) { sc[tid] = ss[tid]; sh[tid] = ss[DD + tid]; }
    __syncthreads();
    long long total = (long long)NN * DD / 4;
    for (long long i = (long long)blockIdx.x * blockDim.x + tid; i < total;
         i += (long long)gridDim.x * blockDim.x) {
        float4 v = ((float4*)h)[i];
        int c = (int)(i & 31) * 4;
        v.x = v.x * sc[c] + sh[c];
        v.y = v.y * sc[c + 1] + sh[c + 1];
        v.z = v.z * sc[c + 2] + sh[c + 2];
        v.w = v.w * sc[c + 3] + sh[c + 3];
        ((float4*)h)[i] = v;
    }
}

// ---------- per-graph max pool over contiguous node range ----------
__global__ void pool_kernel(const float* __restrict__ h, const int* __restrict__ start,
                            float* __restrict__ pooled, int l) {
    int g = blockIdx.x;
    int c = threadIdx.x; // 128
    int lo = start[g], hi = start[g + 1];
    float m = -FLT_MAX;
    for (int n = lo; n < hi; n++) m = fmaxf(m, h[(long long)n * DD + c]);
    pooled[(long long)g * (3 * DD) + l * DD + c] = m;
}

// ---------- final: out = relu(pooled @ w_emb + b_emb), [4096,384]@[384,256] ----------
__global__ __launch_bounds__(256) void emb_kernel(const float* __restrict__ pooled,
                                                  const float* __restrict__ w,
                                                  const float* __restrict__ b,
                                                  float* __restrict__ out) {
    __shared__ float pl[8][384];
    int tid = threadIdx.x;
    int g0 = blockIdx.x * 8;
#pragma unroll
    for (int i = 0; i < 12; i++) {
        int idx = tid + i * 256;           // 0..3071
        int gg = idx / 384, c = idx % 384;
        pl[gg][c] = pooled[(long long)(g0 + gg) * 384 + c];
    }
    __syncthreads();
    float acc[8];
#pragma unroll
    for (int gg = 0; gg < 8; gg++) acc[gg] = 0.f;
    for (int k = 0; k < 384; k++) {
        float wv = w[k * 256 + tid];
#pragma unroll
        for (int gg = 0; gg < 8; gg++) acc[gg] += pl[gg][k] * wv;
    }
    float bb = b[tid];
#pragma unroll
    for (int gg = 0; gg < 8; gg++)
        out[(long long)(g0 + gg) * 256 + tid] = fmaxf(acc[gg] + bb, 0.f);
}

extern "C" void kernel_launch(void* const* d_in, const int* in_sizes, int n_in,
                              void* d_out, int out_size, void* d_ws, size_t ws_size,
                              hipStream_t stream) {
    const float* x = (const float*)d_in[0];
    const void* eidx = d_in[1];
    const void* batch = d_in[2];
    const float* w1[3] = { (const float*)d_in[3],  (const float*)d_in[9],  (const float*)d_in[15] };
    const float* b1[3] = { (const float*)d_in[4],  (const float*)d_in[10], (const float*)d_in[16] };
    const float* w2[3] = { (const float*)d_in[5],  (const float*)d_in[11], (const float*)d_in[17] };
    const float* b2[3] = { (const float*)d_in[6],  (const float*)d_in[12], (const float*)d_in[18] };
    const float* gm[3] = { (const float*)d_in[7],  (const float*)d_in[13], (const float*)d_in[19] };
    const float* bt[3] = { (const float*)d_in[8],  (const float*)d_in[14], (const float*)d_in[20] };
    const float* w_emb = (const float*)d_in[21];
    const float* b_emb = (const float*)d_in[22];
    float* out = (float*)d_out;

    // workspace layout
    float* bufB = (float*)d_ws;                       // N*128 (agg / MLP hidden)
    float* bufH = bufB + (size_t)NN * DD;             // N*128 (layer output h)
    float* pooled = bufH + (size_t)NN * DD;           // G*384
    float* sums = pooled + (size_t)NG * 384;          // 256
    float* ss = sums + 256;                           // 256
    int* start = (int*)(ss + 256);                    // NG+1
    int* flags = start + (NG + 2);                    // 2

    detect_kernel<<<1, 64, 0, stream>>>((const unsigned*)eidx, (const unsigned*)batch, flags);
    graph_starts_kernel<<<(NG + 1 + 255) / 256, 256, 0, stream>>>(batch, flags, start);

    const float* h = x;
    for (int l = 0; l < 3; l++) {
        int K = (l == 0) ? FIN : DD;
        hipMemsetAsync(bufB, 0, (size_t)NN * DD * sizeof(float), stream);
        if (l == 0) {
            long long tot = (long long)NE * FIN;
            scatter_add_kernel<FIN><<<(unsigned)((tot + 255) / 256), 256, 0, stream>>>(h, eidx, flags, bufB);
        } else {
            long long tot = (long long)NE * DD;
            scatter_add_kernel<DD><<<(unsigned)((tot + 255) / 256), 256, 0, stream>>>(h, eidx, flags, bufB);
        }
        // bufB <- relu((h + agg) @ w1 + b1)   (in-place safe: block-private rows)
        gemm_kernel<true, true><<<NN / 64, 256, 0, stream>>>(h, bufB, w1[l], b1[l], bufB, K);
        // bufH <- relu(bufB @ w2 + b2)
        gemm_kernel<false, true><<<NN / 64, 256, 0, stream>>>(bufB, nullptr, w2[l], b2[l], bufH, DD);
        hipMemsetAsync(sums, 0, 256 * sizeof(float), stream);
        bn_reduce_kernel<<<1024, 128, 0, stream>>>(bufH, sums);
        bn_finalize_kernel<<<1, 128, 0, stream>>>(sums, gm[l], bt[l], ss);
        bn_apply_kernel<<<2048, 256, 0, stream>>>(bufH, ss);
        pool_kernel<<<NG, 128, 0, stream>>>(bufH, start, pooled, l);
        h = bufH;
    }
    emb_kernel<<<NG / 8, 256, 0, stream>>>(pooled, w_emb, b_emb, out);
}

// Round 3
// 977.390 us; speedup vs baseline: 2.3448x; 2.3448x over previous
//
#include <hip/hip_runtime.h>
#include <hip/hip_bf16.h>
#include <float.h>

#define NN 200000
#define NE 400000
#define NG 4096
#define FIN 77
#define DD 128
#define BN_EPS 1e-5f

typedef float f32x4 __attribute__((ext_vector_type(4)));
typedef short s16x8 __attribute__((ext_vector_type(8)));

__device__ __forceinline__ unsigned short f2bf(float x) {
    unsigned b = __float_as_uint(x);
    unsigned r = (b + 0x7FFFu + ((b >> 16) & 1u)) >> 16;
    return (unsigned short)r;
}
__device__ __forceinline__ float bf2f(unsigned short u) {
    return __uint_as_float(((unsigned)u) << 16);
}

// ---------- dtype detection (int64 vs int32 index arrays) ----------
__global__ void detect_kernel(const unsigned* eidx, const unsigned* batch, int* flags) {
    if (threadIdx.x == 0 && blockIdx.x == 0) {
        int e64 = 1, b64 = 1;
        for (int i = 0; i < 16; i++) {
            if (eidx[2 * NE - 1 - 2 * i] != 0u) e64 = 0;   // odd word indices at end
            if (batch[NN - 1 - 2 * i] != 0u) b64 = 0;      // NN-1 odd; batch sorted->nonzero if i32
        }
        flags[0] = e64;
        flags[1] = b64;
    }
}

__device__ __forceinline__ int load_idx(const void* p, int is64, long long i) {
    return is64 ? (int)((const long long*)p)[i] : ((const int*)p)[i];
}

// ---------- graph start offsets via binary search (batch sorted) ----------
__global__ void graph_starts_kernel(const void* batch, const int* flags, int* start) {
    int g = blockIdx.x * blockDim.x + threadIdx.x;
    if (g > NG) return;
    int is64 = flags[1];
    int lo = 0, hi = NN;
    while (lo < hi) {
        int mid = (lo + hi) >> 1;
        int v = load_idx(batch, is64, mid);
        if (v < g) lo = mid + 1; else hi = mid;
    }
    start[g] = lo;
}

// ---------- W preconvert: wt[c][k] = bf16(W[k][c]), zero-padded to 128 ----------
__global__ void wconv_kernel(const float* __restrict__ w1, const float* __restrict__ w2,
                             unsigned short* __restrict__ wt1, unsigned short* __restrict__ wt2,
                             int K1) {
    int idx = blockIdx.x * 256 + threadIdx.x;   // 16384
    int c = idx >> 7, k = idx & 127;
    wt1[idx] = f2bf(k < K1 ? w1[k * DD + c] : 0.f);
    wt2[idx] = f2bf(w2[k * DD + c]);
}

// ---------- edge scatter-add: agg[dst] += h[src] ----------
template <int L0>
__global__ void scatter_kernel(const void* __restrict__ hsrc, const void* __restrict__ eidx,
                               const int* __restrict__ flags, float* __restrict__ agg) {
    int e = blockIdx.x * 2 + (threadIdx.x >> 7);
    int c = threadIdx.x & 127;
    int is64 = flags[0];
    int src = load_idx(eidx, is64, e);
    int dst = load_idx(eidx, is64, (long long)NE + e);
    float v;
    if (L0) {
        if (c >= FIN) return;
        v = ((const float*)hsrc)[(long long)src * FIN + c];
    } else {
        v = bf2f(((const unsigned short*)hsrc)[(long long)src * DD + c]);
    }
    atomicAdd(&agg[(long long)dst * DD + c], v);
}

// ---------- MFMA GEMM: Out = relu(X @ W + bias), bf16 in/out ----------
// MODE 0: X = x(fp32,stride 77) + agg(fp32), KSTEPS=3, out stride 256 (hm)
// MODE 1: X = hb(bf16,stride 128) + agg(fp32), KSTEPS=4, out stride 256 (hm)
// MODE 2: X = hm(bf16,stride 256), KSTEPS=4, out stride 256 (hp in-place)
template <int MODE>
__global__ __launch_bounds__(256) void mfma_gemm(
    const float* __restrict__ xf, const unsigned short* __restrict__ xb,
    const float* __restrict__ agg, const unsigned short* __restrict__ wt,
    const float* __restrict__ bias, unsigned short* __restrict__ out)
{
    __shared__ unsigned short Xs[64 * 128];
    __shared__ unsigned short Ws[128 * 128];
    int tid = threadIdx.x;
    int lane = tid & 63;
    int w = tid >> 6;
    long long rowBase = (long long)blockIdx.x * 64;

    // stage W^T [128 cols][128 k] with XOR swizzle
#pragma unroll
    for (int p = 0; p < 8; p++) {
        int u = p * 2048 + tid * 8;
        int c = u >> 7, kc = u & 127;
        s16x8 v = *(const s16x8*)&wt[u];
        *(s16x8*)&Ws[c * 128 + (kc ^ ((c & 7) << 3))] = v;
    }
    // stage X tile [64 rows][128 k] bf16, swizzled
#pragma unroll
    for (int p = 0; p < 4; p++) {
        int r = p * 16 + (tid >> 4);
        int c8 = (tid & 15) * 8;
        long long gr = rowBase + r;
        union { s16x8 v; unsigned short u[8]; } pk;
        if (MODE == 0) {
#pragma unroll
            for (int j = 0; j < 8; j++) {
                int c = c8 + j;
                float vv = (c < FIN) ? (xf[gr * FIN + c] + agg[gr * DD + c]) : 0.f;
                pk.u[j] = f2bf(vv);
            }
        } else if (MODE == 1) {
            s16x8 hv = *(const s16x8*)&xb[gr * 128 + c8];
            f32x4 a0 = *(const f32x4*)&agg[gr * DD + c8];
            f32x4 a1 = *(const f32x4*)&agg[gr * DD + c8 + 4];
#pragma unroll
            for (int j = 0; j < 4; j++) pk.u[j] = f2bf(bf2f((unsigned short)hv[j]) + a0[j]);
#pragma unroll
            for (int j = 0; j < 4; j++) pk.u[4 + j] = f2bf(bf2f((unsigned short)hv[4 + j]) + a1[j]);
        } else {
            pk.v = *(const s16x8*)&xb[gr * 256 + c8];
        }
        *(s16x8*)&Xs[r * 128 + (c8 ^ ((r & 7) << 3))] = pk.v;
    }
    __syncthreads();

    constexpr int KSTEPS = (MODE == 0) ? 3 : 4;
    f32x4 acc[4][2];
#pragma unroll
    for (int rb = 0; rb < 4; rb++)
#pragma unroll
        for (int cb = 0; cb < 2; cb++) acc[rb][cb] = 0;

#pragma unroll
    for (int ks = 0; ks < KSTEPS; ks++) {
        int lk = ks * 32 + (lane >> 4) * 8;
        s16x8 af[4];
#pragma unroll
        for (int rb = 0; rb < 4; rb++) {
            int r = rb * 16 + (lane & 15);
            af[rb] = *(const s16x8*)&Xs[r * 128 + (lk ^ ((r & 7) << 3))];
        }
        s16x8 bfr[2];
#pragma unroll
        for (int cb = 0; cb < 2; cb++) {
            int col = w * 32 + cb * 16 + (lane & 15);
            bfr[cb] = *(const s16x8*)&Ws[col * 128 + (lk ^ ((col & 7) << 3))];
        }
#pragma unroll
        for (int rb = 0; rb < 4; rb++)
#pragma unroll
            for (int cb = 0; cb < 2; cb++)
                acc[rb][cb] = __builtin_amdgcn_mfma_f32_16x16x32_bf16(af[rb], bfr[cb], acc[rb][cb], 0, 0, 0);
    }

    float bs[2];
#pragma unroll
    for (int cb = 0; cb < 2; cb++) bs[cb] = bias[w * 32 + cb * 16 + (lane & 15)];
#pragma unroll
    for (int rb = 0; rb < 4; rb++)
#pragma unroll
        for (int cb = 0; cb < 2; cb++)
#pragma unroll
            for (int reg = 0; reg < 4; reg++) {
                long long row = rowBase + rb * 16 + (lane >> 4) * 4 + reg;
                int col = w * 32 + cb * 16 + (lane & 15);
                float v = acc[rb][cb][reg] + bs[cb];
                v = fmaxf(v, 0.f);
                out[row * 256 + col] = f2bf(v);
            }
}

// ---------- BN reduce over strided bf16 hp (row stride 256 ushorts) ----------
__global__ __launch_bounds__(256) void bn_reduce_kernel(const unsigned short* __restrict__ hp,
                                                        float* __restrict__ sums) {
    __shared__ float red[16][132];
    int tid = threadIdx.x;
    int rg = tid >> 4;
    int c8 = (tid & 15) * 8;
    float s[8], q[8];
#pragma unroll
    for (int j = 0; j < 8; j++) { s[j] = 0.f; q[j] = 0.f; }
    for (long long r0 = (long long)blockIdx.x * 16; r0 < NN; r0 += (long long)gridDim.x * 16) {
        long long r = r0 + rg;
        s16x8 v = *(const s16x8*)&hp[r * 256 + c8];
#pragma unroll
        for (int j = 0; j < 8; j++) {
            float f = bf2f((unsigned short)v[j]);
            s[j] += f; q[j] += f * f;
        }
    }
#pragma unroll
    for (int j = 0; j < 8; j++) red[rg][c8 + j] = s[j];
    __syncthreads();
    if (tid < 128) {
        float t = 0.f;
#pragma unroll
        for (int g = 0; g < 16; g++) t += red[g][tid];
        atomicAdd(&sums[tid], t);
    }
    __syncthreads();
#pragma unroll
    for (int j = 0; j < 8; j++) red[rg][c8 + j] = q[j];
    __syncthreads();
    if (tid < 128) {
        float t = 0.f;
#pragma unroll
        for (int g = 0; g < 16; g++) t += red[g][tid];
        atomicAdd(&sums[DD + tid], t);
    }
}

__global__ void bn_finalize_kernel(const float* __restrict__ sums,
                                   const float* __restrict__ gamma,
                                   const float* __restrict__ beta,
                                   float* __restrict__ ss) {
    int c = threadIdx.x;
    float mu = sums[c] / (float)NN;
    float var = sums[DD + c] / (float)NN - mu * mu;
    float sc = gamma[c] * rsqrtf(var + BN_EPS);
    ss[c] = sc;
    ss[DD + c] = beta[c] - mu * sc;
}

// ---------- BN apply: hp(strided bf16) -> hb(contiguous bf16) ----------
__global__ __launch_bounds__(256) void bn_apply_kernel(const unsigned short* __restrict__ hp,
                                                       const float* __restrict__ ss,
                                                       unsigned short* __restrict__ hb) {
    __shared__ float sc[DD], sh[DD];
    int tid = threadIdx.x;
    if (tid < DD) { sc[tid] = ss[tid]; sh[tid] = ss[DD + tid]; }
    __syncthreads();
    long long total = (long long)NN * 16;
    for (long long i = (long long)blockIdx.x * blockDim.x + tid; i < total;
         i += (long long)gridDim.x * blockDim.x) {
        long long r = i >> 4;
        int c8 = (int)(i & 15) * 8;
        s16x8 v = *(const s16x8*)&hp[r * 256 + c8];
        union { s16x8 v; unsigned short u[8]; } o;
#pragma unroll
        for (int j = 0; j < 8; j++) {
            float f = bf2f((unsigned short)v[j]);
            o.u[j] = f2bf(f * sc[c8 + j] + sh[c8 + j]);
        }
        *(s16x8*)&hb[r * 128 + c8] = o.v;
    }
}

// ---------- per-graph max pool (contiguous node range), bf16 in, fp32 out ----------
__global__ void pool_kernel(const unsigned short* __restrict__ hb, const int* __restrict__ start,
                            float* __restrict__ pooled, int l) {
    int g = blockIdx.x;
    int c = threadIdx.x; // 128
    int lo = start[g], hi = start[g + 1];
    float m = -FLT_MAX;
    for (int n = lo; n < hi; n++) m = fmaxf(m, bf2f(hb[(long long)n * DD + c]));
    pooled[(long long)g * (3 * DD) + l * DD + c] = m;
}

// ---------- final: out = relu(pooled @ w_emb + b_emb), [4096,384]@[384,256] ----------
__global__ __launch_bounds__(256) void emb_kernel(const float* __restrict__ pooled,
                                                  const float* __restrict__ w,
                                                  const float* __restrict__ b,
                                                  float* __restrict__ out) {
    __shared__ float pl[8][384];
    int tid = threadIdx.x;
    int g0 = blockIdx.x * 8;
#pragma unroll
    for (int i = 0; i < 12; i++) {
        int idx = tid + i * 256;
        int gg = idx / 384, c = idx % 384;
        pl[gg][c] = pooled[(long long)(g0 + gg) * 384 + c];
    }
    __syncthreads();
    float acc[8];
#pragma unroll
    for (int gg = 0; gg < 8; gg++) acc[gg] = 0.f;
    for (int k = 0; k < 384; k++) {
        float wv = w[k * 256 + tid];
#pragma unroll
        for (int gg = 0; gg < 8; gg++) acc[gg] += pl[gg][k] * wv;
    }
    float bb = b[tid];
#pragma unroll
    for (int gg = 0; gg < 8; gg++)
        out[(long long)(g0 + gg) * 256 + tid] = fmaxf(acc[gg] + bb, 0.f);
}

extern "C" void kernel_launch(void* const* d_in, const int* in_sizes, int n_in,
                              void* d_out, int out_size, void* d_ws, size_t ws_size,
                              hipStream_t stream) {
    const float* x = (const float*)d_in[0];
    const void* eidx = d_in[1];
    const void* batch = d_in[2];
    const float* w1[3] = { (const float*)d_in[3],  (const float*)d_in[9],  (const float*)d_in[15] };
    const float* b1[3] = { (const float*)d_in[4],  (const float*)d_in[10], (const float*)d_in[16] };
    const float* w2[3] = { (const float*)d_in[5],  (const float*)d_in[11], (const float*)d_in[17] };
    const float* b2[3] = { (const float*)d_in[6],  (const float*)d_in[12], (const float*)d_in[18] };
    const float* gm[3] = { (const float*)d_in[7],  (const float*)d_in[13], (const float*)d_in[19] };
    const float* bt[3] = { (const float*)d_in[8],  (const float*)d_in[14], (const float*)d_in[20] };
    const float* w_emb = (const float*)d_in[21];
    const float* b_emb = (const float*)d_in[22];
    float* out = (float*)d_out;

    // workspace layout (all 16B aligned)
    float* agg = (float*)d_ws;                               // N*128 fp32 (doubles as hm/hp strided bf16)
    unsigned short* hb = (unsigned short*)(agg + (size_t)NN * DD);   // N*128 bf16
    float* pooled = (float*)(hb + (size_t)NN * DD);          // G*384 fp32
    unsigned short* wt1 = (unsigned short*)(pooled + (size_t)NG * 384); // 128*128 bf16
    unsigned short* wt2 = wt1 + 128 * 128;                   // 128*128 bf16
    float* sums = (float*)(wt2 + 128 * 128);                 // 256
    float* ss = sums + 256;                                  // 256
    int* start = (int*)(ss + 256);                           // NG+1
    int* flags = start + (NG + 2);                           // 2

    unsigned short* hm = (unsigned short*)agg;               // strided bf16 (row stride 256)

    detect_kernel<<<1, 64, 0, stream>>>((const unsigned*)eidx, (const unsigned*)batch, flags);
    graph_starts_kernel<<<(NG + 1 + 255) / 256, 256, 0, stream>>>(batch, flags, start);

    for (int l = 0; l < 3; l++) {
        wconv_kernel<<<64, 256, 0, stream>>>(w1[l], w2[l], wt1, wt2, (l == 0) ? FIN : DD);
        hipMemsetAsync(agg, 0, (size_t)NN * DD * sizeof(float), stream);
        if (l == 0)
            scatter_kernel<1><<<NE / 2, 256, 0, stream>>>(x, eidx, flags, agg);
        else
            scatter_kernel<0><<<NE / 2, 256, 0, stream>>>(hb, eidx, flags, agg);

        if (l == 0)
            mfma_gemm<0><<<NN / 64, 256, 0, stream>>>(x, nullptr, agg, wt1, b1[l], hm);
        else
            mfma_gemm<1><<<NN / 64, 256, 0, stream>>>(nullptr, hb, agg, wt1, b1[l], hm);
        mfma_gemm<2><<<NN / 64, 256, 0, stream>>>(nullptr, hm, nullptr, wt2, b2[l], hm);

        hipMemsetAsync(sums, 0, 256 * sizeof(float), stream);
        bn_reduce_kernel<<<512, 256, 0, stream>>>(hm, sums);
        bn_finalize_kernel<<<1, 128, 0, stream>>>(sums, gm[l], bt[l], ss);
        bn_apply_kernel<<<1024, 256, 0, stream>>>(hm, ss, hb);
        pool_kernel<<<NG, 128, 0, stream>>>(hb, start, pooled, l);
    }
    emb_kernel<<<NG / 8, 256, 0, stream>>>(pooled, w_emb, b_emb, out);
}

// Round 4
// 671.521 us; speedup vs baseline: 3.4128x; 1.4555x over previous
//
#include <hip/hip_runtime.h>
#include <hip/hip_bf16.h>
#include <float.h>

#define NN 200000
#define NE 400000
#define NG 4096
#define FIN 77
#define DD 128
#define BN_EPS 1e-5f
#define NB_SCAN ((NN + 255) / 256)   // 782

typedef float f32x4 __attribute__((ext_vector_type(4)));
typedef short s16x8 __attribute__((ext_vector_type(8)));

__device__ __forceinline__ unsigned short f2bf(float x) {
    unsigned b = __float_as_uint(x);
    unsigned r = (b + 0x7FFFu + ((b >> 16) & 1u)) >> 16;
    return (unsigned short)r;
}
__device__ __forceinline__ float bf2f(unsigned short u) {
    return __uint_as_float(((unsigned)u) << 16);
}

// ---------- dtype detection (int64 vs int32 index arrays) ----------
__global__ void detect_kernel(const unsigned* eidx, const unsigned* batch, int* flags) {
    if (threadIdx.x == 0 && blockIdx.x == 0) {
        int e64 = 1, b64 = 1;
        for (int i = 0; i < 16; i++) {
            if (eidx[2 * NE - 1 - 2 * i] != 0u) e64 = 0;   // odd word indices at end
            if (batch[NN - 1 - 2 * i] != 0u) b64 = 0;      // batch sorted -> end nonzero if i32
        }
        flags[0] = e64;
        flags[1] = b64;
    }
}

__device__ __forceinline__ int load_idx(const void* p, int is64, long long i) {
    return is64 ? (int)((const long long*)p)[i] : ((const int*)p)[i];
}

// ---------- graph start offsets via binary search (batch sorted) ----------
__global__ void graph_starts_kernel(const void* batch, const int* flags, int* start) {
    int g = blockIdx.x * blockDim.x + threadIdx.x;
    if (g > NG) return;
    int is64 = flags[1];
    int lo = 0, hi = NN;
    while (lo < hi) {
        int mid = (lo + hi) >> 1;
        int v = load_idx(batch, is64, mid);
        if (v < g) lo = mid + 1; else hi = mid;
    }
    start[g] = lo;
}

// ---------- CSR build ----------
__global__ void count_kernel(const void* __restrict__ eidx, const int* __restrict__ flags,
                             int* __restrict__ deg) {
    int e = blockIdx.x * 256 + threadIdx.x;
    if (e >= NE) return;
    int dst = load_idx(eidx, flags[0], (long long)NE + e);
    atomicAdd(&deg[dst], 1);
}

__global__ void scan1_kernel(const int* __restrict__ deg, int* __restrict__ incl,
                             int* __restrict__ bsum) {
    __shared__ int sh[256];
    int i = blockIdx.x * 256 + threadIdx.x;
    int v = (i < NN) ? deg[i] : 0;
    sh[threadIdx.x] = v;
    __syncthreads();
    for (int off = 1; off < 256; off <<= 1) {
        int t = (threadIdx.x >= off) ? sh[threadIdx.x - off] : 0;
        __syncthreads();
        sh[threadIdx.x] += t;
        __syncthreads();
    }
    if (i < NN) incl[i] = sh[threadIdx.x];
    if (threadIdx.x == 255) bsum[blockIdx.x] = sh[255];
}

__global__ void scan2_kernel(int* __restrict__ bsum) {
    __shared__ int sh[NB_SCAN];
    for (int i = threadIdx.x; i < NB_SCAN; i += blockDim.x) sh[i] = bsum[i];
    __syncthreads();
    if (threadIdx.x == 0) {
        int acc = 0;
        for (int i = 0; i < NB_SCAN; i++) { int t = sh[i]; sh[i] = acc; acc += t; }
    }
    __syncthreads();
    for (int i = threadIdx.x; i < NB_SCAN; i += blockDim.x) bsum[i] = sh[i];
}

__global__ void scan3_kernel(const int* __restrict__ incl, const int* __restrict__ deg,
                             const int* __restrict__ bsum, int* __restrict__ rowptr,
                             int* __restrict__ cursor) {
    int i = blockIdx.x * 256 + threadIdx.x;
    if (i < NN) {
        int ex = bsum[blockIdx.x] + incl[i] - deg[i];
        rowptr[i] = ex;
        cursor[i] = ex;
    }
    if (i == 0) rowptr[NN] = NE;
}

__global__ void fill_kernel(const void* __restrict__ eidx, const int* __restrict__ flags,
                            int* __restrict__ cursor, int* __restrict__ slots) {
    int e = blockIdx.x * 256 + threadIdx.x;
    if (e >= NE) return;
    int is64 = flags[0];
    int src = load_idx(eidx, is64, e);
    int dst = load_idx(eidx, is64, (long long)NE + e);
    int pos = atomicAdd(&cursor[dst], 1);
    slots[pos] = src;
}

// ---------- W preconvert: wt[c][k] = bf16(W[k][c]), zero-padded to 128 ----------
__global__ void wconv_kernel(const float* __restrict__ w1, const float* __restrict__ w2,
                             unsigned short* __restrict__ wt1, unsigned short* __restrict__ wt2,
                             int K1) {
    int idx = blockIdx.x * 256 + threadIdx.x;   // 16384
    int c = idx >> 7, k = idx & 127;
    wt1[idx] = f2bf(k < K1 ? w1[k * DD + c] : 0.f);
    wt2[idx] = f2bf(w2[k * DD + c]);
}

// ---------- CSR gather-aggregate, fused self-term + previous-layer BN affine ----------
// L0: xs[row][c] = x[row][c] + sum_src x[src][c]            (c<77, else 0)
// else: norm(v)=v*sc[c]+sh[c];  xs[row][c] = norm(hm[row][c]) + sum_src norm(hm[src][c])
template <int L0>
__global__ __launch_bounds__(256) void agg_kernel(
    const float* __restrict__ xf, const unsigned short* __restrict__ hm,
    const float* __restrict__ ss,
    const int* __restrict__ rowptr, const int* __restrict__ slots,
    unsigned short* __restrict__ xs)
{
    int row = blockIdx.x * 2 + (threadIdx.x >> 7);
    int c = threadIdx.x & 127;
    int lo = rowptr[row], hi = rowptr[row + 1];
    float s;
    if (L0) {
        if (c < FIN) {
            s = xf[(long long)row * FIN + c];
            for (int k = lo; k < hi; k++) {
                int src = slots[k];
                s += xf[(long long)src * FIN + c];
            }
        } else {
            s = 0.f;
        }
    } else {
        float sc = ss[c], sh = ss[DD + c];
        s = bf2f(hm[(long long)row * DD + c]) * sc + sh;
        for (int k = lo; k < hi; k++) {
            int src = slots[k];
            s += bf2f(hm[(long long)src * DD + c]) * sc + sh;
        }
    }
    xs[(long long)row * DD + c] = f2bf(s);
}

// ---------- MFMA GEMM: out = relu(in @ W + bias), bf16 [N,128] -> bf16 [N,128] ----------
template <int KSTEPS>
__global__ __launch_bounds__(256) void mfma_gemm(
    const unsigned short* __restrict__ xb, const unsigned short* __restrict__ wt,
    const float* __restrict__ bias, unsigned short* __restrict__ out)
{
    __shared__ unsigned short Xs[64 * 128];
    __shared__ unsigned short Ws[128 * 128];
    int tid = threadIdx.x;
    int lane = tid & 63;
    int w = tid >> 6;
    long long rowBase = (long long)blockIdx.x * 64;

    // stage W^T [128 cols][128 k], XOR swizzle
#pragma unroll
    for (int p = 0; p < 8; p++) {
        int u = p * 2048 + tid * 8;
        int c = u >> 7, kc = u & 127;
        s16x8 v = *(const s16x8*)&wt[u];
        *(s16x8*)&Ws[c * 128 + (kc ^ ((c & 7) << 3))] = v;
    }
    // stage X tile [64 rows][128 k], XOR swizzle
#pragma unroll
    for (int p = 0; p < 4; p++) {
        int r = p * 16 + (tid >> 4);
        int c8 = (tid & 15) * 8;
        s16x8 v = *(const s16x8*)&xb[(rowBase + r) * DD + c8];
        *(s16x8*)&Xs[r * 128 + (c8 ^ ((r & 7) << 3))] = v;
    }
    __syncthreads();

    f32x4 acc[4][2];
#pragma unroll
    for (int rb = 0; rb < 4; rb++)
#pragma unroll
        for (int cb = 0; cb < 2; cb++) acc[rb][cb] = 0;

#pragma unroll
    for (int ks = 0; ks < KSTEPS; ks++) {
        int lk = ks * 32 + (lane >> 4) * 8;
        s16x8 af[4];
#pragma unroll
        for (int rb = 0; rb < 4; rb++) {
            int r = rb * 16 + (lane & 15);
            af[rb] = *(const s16x8*)&Xs[r * 128 + (lk ^ ((r & 7) << 3))];
        }
        s16x8 bfr[2];
#pragma unroll
        for (int cb = 0; cb < 2; cb++) {
            int col = w * 32 + cb * 16 + (lane & 15);
            bfr[cb] = *(const s16x8*)&Ws[col * 128 + (lk ^ ((col & 7) << 3))];
        }
#pragma unroll
        for (int rb = 0; rb < 4; rb++)
#pragma unroll
            for (int cb = 0; cb < 2; cb++)
                acc[rb][cb] = __builtin_amdgcn_mfma_f32_16x16x32_bf16(af[rb], bfr[cb], acc[rb][cb], 0, 0, 0);
    }

    float bs[2];
#pragma unroll
    for (int cb = 0; cb < 2; cb++) bs[cb] = bias[w * 32 + cb * 16 + (lane & 15)];
#pragma unroll
    for (int rb = 0; rb < 4; rb++)
#pragma unroll
        for (int cb = 0; cb < 2; cb++)
#pragma unroll
            for (int reg = 0; reg < 4; reg++) {
                long long row = rowBase + rb * 16 + (lane >> 4) * 4 + reg;
                int col = w * 32 + cb * 16 + (lane & 15);
                float v = fmaxf(acc[rb][cb][reg] + bs[cb], 0.f);
                out[row * DD + col] = f2bf(v);
            }
}

// ---------- BN: column sums / sumsq over contiguous bf16 [N,128] ----------
__global__ __launch_bounds__(256) void bn_reduce_kernel(const unsigned short* __restrict__ hm,
                                                        float* __restrict__ sums) {
    __shared__ float red[16][132];
    int tid = threadIdx.x;
    int rg = tid >> 4;
    int c8 = (tid & 15) * 8;
    float s[8], q[8];
#pragma unroll
    for (int j = 0; j < 8; j++) { s[j] = 0.f; q[j] = 0.f; }
    for (long long r0 = (long long)blockIdx.x * 16; r0 < NN; r0 += (long long)gridDim.x * 16) {
        long long r = r0 + rg;
        s16x8 v = *(const s16x8*)&hm[r * DD + c8];
#pragma unroll
        for (int j = 0; j < 8; j++) {
            float f = bf2f((unsigned short)v[j]);
            s[j] += f; q[j] += f * f;
        }
    }
#pragma unroll
    for (int j = 0; j < 8; j++) red[rg][c8 + j] = s[j];
    __syncthreads();
    if (tid < 128) {
        float t = 0.f;
#pragma unroll
        for (int g = 0; g < 16; g++) t += red[g][tid];
        atomicAdd(&sums[tid], t);
    }
    __syncthreads();
#pragma unroll
    for (int j = 0; j < 8; j++) red[rg][c8 + j] = q[j];
    __syncthreads();
    if (tid < 128) {
        float t = 0.f;
#pragma unroll
        for (int g = 0; g < 16; g++) t += red[g][tid];
        atomicAdd(&sums[DD + tid], t);
    }
}

__global__ void bn_finalize_kernel(const float* __restrict__ sums,
                                   const float* __restrict__ gamma,
                                   const float* __restrict__ beta,
                                   float* __restrict__ ss) {
    int c = threadIdx.x;
    float mu = sums[c] / (float)NN;
    float var = sums[DD + c] / (float)NN - mu * mu;
    float sc = gamma[c] * rsqrtf(var + BN_EPS);
    ss[c] = sc;
    ss[DD + c] = beta[c] - mu * sc;
}

// ---------- per-graph max pool with on-the-fly BN affine ----------
__global__ void pool_kernel(const unsigned short* __restrict__ hm, const float* __restrict__ ss,
                            const int* __restrict__ start, float* __restrict__ pooled, int l) {
    int g = blockIdx.x;
    int c = threadIdx.x; // 128
    int lo = start[g], hi = start[g + 1];
    float sc = ss[c], sh = ss[DD + c];
    float m = -FLT_MAX;
    for (int n = lo; n < hi; n++)
        m = fmaxf(m, bf2f(hm[(long long)n * DD + c]) * sc + sh);
    pooled[(long long)g * (3 * DD) + l * DD + c] = m;
}

// ---------- final: out = relu(pooled @ w_emb + b_emb), [4096,384]@[384,256] ----------
__global__ __launch_bounds__(256) void emb_kernel(const float* __restrict__ pooled,
                                                  const float* __restrict__ w,
                                                  const float* __restrict__ b,
                                                  float* __restrict__ out) {
    __shared__ float pl[8][384];
    int tid = threadIdx.x;
    int g0 = blockIdx.x * 8;
#pragma unroll
    for (int i = 0; i < 12; i++) {
        int idx = tid + i * 256;
        int gg = idx / 384, c = idx % 384;
        pl[gg][c] = pooled[(long long)(g0 + gg) * 384 + c];
    }
    __syncthreads();
    float acc[8];
#pragma unroll
    for (int gg = 0; gg < 8; gg++) acc[gg] = 0.f;
    for (int k = 0; k < 384; k++) {
        float wv = w[k * 256 + tid];
#pragma unroll
        for (int gg = 0; gg < 8; gg++) acc[gg] += pl[gg][k] * wv;
    }
    float bb = b[tid];
#pragma unroll
    for (int gg = 0; gg < 8; gg++)
        out[(long long)(g0 + gg) * 256 + tid] = fmaxf(acc[gg] + bb, 0.f);
}

extern "C" void kernel_launch(void* const* d_in, const int* in_sizes, int n_in,
                              void* d_out, int out_size, void* d_ws, size_t ws_size,
                              hipStream_t stream) {
    const float* x = (const float*)d_in[0];
    const void* eidx = d_in[1];
    const void* batch = d_in[2];
    const float* w1[3] = { (const float*)d_in[3],  (const float*)d_in[9],  (const float*)d_in[15] };
    const float* b1[3] = { (const float*)d_in[4],  (const float*)d_in[10], (const float*)d_in[16] };
    const float* w2[3] = { (const float*)d_in[5],  (const float*)d_in[11], (const float*)d_in[17] };
    const float* b2[3] = { (const float*)d_in[6],  (const float*)d_in[12], (const float*)d_in[18] };
    const float* gm[3] = { (const float*)d_in[7],  (const float*)d_in[13], (const float*)d_in[19] };
    const float* bt[3] = { (const float*)d_in[8],  (const float*)d_in[14], (const float*)d_in[20] };
    const float* w_emb = (const float*)d_in[21];
    const float* b_emb = (const float*)d_in[22];
    float* out = (float*)d_out;

    // workspace layout
    unsigned short* xs = (unsigned short*)d_ws;              // N*128 bf16
    unsigned short* hm = xs + (size_t)NN * DD;               // N*128 bf16
    float* pooled = (float*)(hm + (size_t)NN * DD);          // G*384 f32
    unsigned short* wt1 = (unsigned short*)(pooled + (size_t)NG * 384);
    unsigned short* wt2 = wt1 + DD * DD;
    float* sums = (float*)(wt2 + DD * DD);                   // 256
    float* ss = sums + 256;                                  // 256
    int* start = (int*)(ss + 256);                           // NG+1
    int* flags = start + NG + 1;                             // 2
    int* deg = flags + 2;                                    // NN
    int* incl = deg + NN;                                    // NN
    int* bsum = incl + NN;                                   // NB_SCAN
    int* rowptr = bsum + NB_SCAN;                            // NN+1
    int* cursor = rowptr + NN + 1;                           // NN
    int* slots = cursor + NN;                                // NE

    detect_kernel<<<1, 64, 0, stream>>>((const unsigned*)eidx, (const unsigned*)batch, flags);
    graph_starts_kernel<<<(NG + 1 + 255) / 256, 256, 0, stream>>>(batch, flags, start);

    // CSR build (once; edge_index is layer-invariant)
    hipMemsetAsync(deg, 0, (size_t)NN * sizeof(int), stream);
    count_kernel<<<(NE + 255) / 256, 256, 0, stream>>>(eidx, flags, deg);
    scan1_kernel<<<NB_SCAN, 256, 0, stream>>>(deg, incl, bsum);
    scan2_kernel<<<1, 1024, 0, stream>>>(bsum);
    scan3_kernel<<<NB_SCAN, 256, 0, stream>>>(incl, deg, bsum, rowptr, cursor);
    fill_kernel<<<(NE + 255) / 256, 256, 0, stream>>>(eidx, flags, cursor, slots);

    for (int l = 0; l < 3; l++) {
        wconv_kernel<<<64, 256, 0, stream>>>(w1[l], w2[l], wt1, wt2, (l == 0) ? FIN : DD);
        if (l == 0)
            agg_kernel<1><<<NN / 2, 256, 0, stream>>>(x, nullptr, nullptr, rowptr, slots, xs);
        else
            agg_kernel<0><<<NN / 2, 256, 0, stream>>>(nullptr, hm, ss, rowptr, slots, xs);

        if (l == 0)
            mfma_gemm<3><<<NN / 64, 256, 0, stream>>>(xs, wt1, b1[l], hm);
        else
            mfma_gemm<4><<<NN / 64, 256, 0, stream>>>(xs, wt1, b1[l], hm);
        mfma_gemm<4><<<NN / 64, 256, 0, stream>>>(hm, wt2, b2[l], hm);   // in-place (block-private rows)

        hipMemsetAsync(sums, 0, 256 * sizeof(float), stream);
        bn_reduce_kernel<<<512, 256, 0, stream>>>(hm, sums);
        bn_finalize_kernel<<<1, 128, 0, stream>>>(sums, gm[l], bt[l], ss);
        pool_kernel<<<NG, 128, 0, stream>>>(hm, ss, start, pooled, l);
    }
    emb_kernel<<<NG / 8, 256, 0, stream>>>(pooled, w_emb, b_emb, out);
}

// Round 5
// 438.254 us; speedup vs baseline: 5.2293x; 1.5323x over previous
//
#include <hip/hip_runtime.h>
#include <hip/hip_bf16.h>
#include <float.h>

#define NN 200000
#define NE 400000
#define NG 4096
#define FIN 77
#define DD 128
#define BN_EPS 1e-5f
#define NB_SCAN ((NN + 255) / 256)   // 782
#define NBLK (NN / 64)               // 3125 fused blocks

typedef float f32x4 __attribute__((ext_vector_type(4)));
typedef short s16x8 __attribute__((ext_vector_type(8)));

__device__ __forceinline__ unsigned short f2bf(float x) {
    unsigned b = __float_as_uint(x);
    unsigned r = (b + 0x7FFFu + ((b >> 16) & 1u)) >> 16;
    return (unsigned short)r;
}
__device__ __forceinline__ float bf2f(unsigned short u) {
    return __uint_as_float(((unsigned)u) << 16);
}

// ---------- dtype detection (int64 vs int32 index arrays) ----------
__global__ void detect_kernel(const unsigned* eidx, const unsigned* batch, int* flags) {
    if (threadIdx.x == 0 && blockIdx.x == 0) {
        int e64 = 1, b64 = 1;
        for (int i = 0; i < 16; i++) {
            if (eidx[2 * NE - 1 - 2 * i] != 0u) e64 = 0;   // odd word indices at end
            if (batch[NN - 1 - 2 * i] != 0u) b64 = 0;      // batch sorted -> end nonzero if i32
        }
        flags[0] = e64;
        flags[1] = b64;
    }
}

__device__ __forceinline__ int load_idx(const void* p, int is64, long long i) {
    return is64 ? (int)((const long long*)p)[i] : ((const int*)p)[i];
}

// ---------- graph start offsets via binary search (batch sorted) ----------
__global__ void graph_starts_kernel(const void* batch, const int* flags, int* start) {
    int g = blockIdx.x * blockDim.x + threadIdx.x;
    if (g > NG) return;
    int is64 = flags[1];
    int lo = 0, hi = NN;
    while (lo < hi) {
        int mid = (lo + hi) >> 1;
        int v = load_idx(batch, is64, mid);
        if (v < g) lo = mid + 1; else hi = mid;
    }
    start[g] = lo;
}

// ---------- CSR build ----------
__global__ void count_kernel(const void* __restrict__ eidx, const int* __restrict__ flags,
                             int* __restrict__ deg) {
    int e = blockIdx.x * 256 + threadIdx.x;
    if (e >= NE) return;
    int dst = load_idx(eidx, flags[0], (long long)NE + e);
    atomicAdd(&deg[dst], 1);
}

__global__ void scan1_kernel(const int* __restrict__ deg, int* __restrict__ incl,
                             int* __restrict__ bsum) {
    __shared__ int sh[256];
    int i = blockIdx.x * 256 + threadIdx.x;
    int v = (i < NN) ? deg[i] : 0;
    sh[threadIdx.x] = v;
    __syncthreads();
    for (int off = 1; off < 256; off <<= 1) {
        int t = (threadIdx.x >= off) ? sh[threadIdx.x - off] : 0;
        __syncthreads();
        sh[threadIdx.x] += t;
        __syncthreads();
    }
    if (i < NN) incl[i] = sh[threadIdx.x];
    if (threadIdx.x == 255) bsum[blockIdx.x] = sh[255];
}

__global__ void scan2_kernel(int* __restrict__ bsum) {
    __shared__ int sh[NB_SCAN];
    for (int i = threadIdx.x; i < NB_SCAN; i += blockDim.x) sh[i] = bsum[i];
    __syncthreads();
    if (threadIdx.x == 0) {
        int acc = 0;
        for (int i = 0; i < NB_SCAN; i++) { int t = sh[i]; sh[i] = acc; acc += t; }
    }
    __syncthreads();
    for (int i = threadIdx.x; i < NB_SCAN; i += blockDim.x) bsum[i] = sh[i];
}

__global__ void scan3_kernel(const int* __restrict__ incl, const int* __restrict__ deg,
                             const int* __restrict__ bsum, int* __restrict__ rowptr,
                             int* __restrict__ cursor) {
    int i = blockIdx.x * 256 + threadIdx.x;
    if (i < NN) {
        int ex = bsum[blockIdx.x] + incl[i] - deg[i];
        rowptr[i] = ex;
        cursor[i] = ex;
    }
    if (i == 0) rowptr[NN] = NE;
}

__global__ void fill_kernel(const void* __restrict__ eidx, const int* __restrict__ flags,
                            int* __restrict__ cursor, int* __restrict__ slots) {
    int e = blockIdx.x * 256 + threadIdx.x;
    if (e >= NE) return;
    int is64 = flags[0];
    int src = load_idx(eidx, is64, e);
    int dst = load_idx(eidx, is64, (long long)NE + e);
    int pos = atomicAdd(&cursor[dst], 1);
    slots[pos] = src;
}

// ---------- x -> bf16 padded [N,96] ----------
__global__ void xconv_kernel(const float* __restrict__ x, unsigned short* __restrict__ xb) {
    int idx = blockIdx.x * 256 + threadIdx.x;       // NN*12 chunks exactly
    int row = idx / 12, c8 = (idx % 12) * 8;
    union { s16x8 v; unsigned short u[8]; } pk;
#pragma unroll
    for (int j = 0; j < 8; j++) {
        int c = c8 + j;
        pk.u[j] = (c < FIN) ? f2bf(x[(long long)row * FIN + c]) : (unsigned short)0;
    }
    *(s16x8*)&xb[(long long)row * 96 + c8] = pk.v;
}

// ---------- W preconvert: wt[c][k] = bf16(W[k][c]), zero-padded to 128 ----------
__global__ void wconv_kernel(const float* __restrict__ w1, const float* __restrict__ w2,
                             unsigned short* __restrict__ wt1, unsigned short* __restrict__ wt2,
                             int K1) {
    int idx = blockIdx.x * 256 + threadIdx.x;   // 16384
    int c = idx >> 7, k = idx & 127;
    wt1[idx] = f2bf(k < K1 ? w1[k * DD + c] : 0.f);
    wt2[idx] = f2bf(w2[k * DD + c]);
}

// ---------- fused layer: gather(+BN affine) -> GEMM1 -> GEMM2 -> h + BN partials ----------
// L0: src = xb [N,96] bf16 (no affine). else: src = hm_prev [N,128] bf16, affine v*sc+sh.
template <int L0>
__global__ __launch_bounds__(256) void fused_layer(
    const unsigned short* __restrict__ src, const float* __restrict__ ss,
    const int* __restrict__ rowptr, const int* __restrict__ slots,
    const unsigned short* __restrict__ wt1, const unsigned short* __restrict__ wt2,
    const float* __restrict__ b1, const float* __restrict__ b2,
    unsigned short* __restrict__ out, float* __restrict__ partials)
{
    __shared__ unsigned short Xs[64 * 128];
    constexpr int SK = L0 ? 96 : 128;
    constexpr int KS1 = L0 ? 3 : 4;
    int tid = threadIdx.x;
    int lane = tid & 63;
    int w = tid >> 6;
    long long rowBase = (long long)blockIdx.x * 64;

    // ---- gather + aggregate + stage Xs (16 threads/row, 8 cols each) ----
    {
        int rp = tid >> 4;
        int ci = tid & 15;
        int c8 = ci * 8;
        float sc[8], sh[8];
        if (!L0) {
#pragma unroll
            for (int j = 0; j < 8; j++) { sc[j] = ss[c8 + j]; sh[j] = ss[DD + c8 + j]; }
        }
#pragma unroll
        for (int p = 0; p < 4; p++) {
            int r = p * 16 + rp;
            long long gr = rowBase + r;
            float a[8];
            if (L0 && c8 >= 96) {
#pragma unroll
                for (int j = 0; j < 8; j++) a[j] = 0.f;
            } else {
                int lo = rowptr[gr], hi = rowptr[gr + 1];
                s16x8 v = *(const s16x8*)&src[gr * SK + c8];
                if (L0) {
#pragma unroll
                    for (int j = 0; j < 8; j++) a[j] = bf2f((unsigned short)v[j]);
                } else {
#pragma unroll
                    for (int j = 0; j < 8; j++) a[j] = bf2f((unsigned short)v[j]) * sc[j] + sh[j];
                }
                int k = lo;
                for (; k + 1 < hi; k += 2) {
                    long long s0 = slots[k], s1 = slots[k + 1];
                    s16x8 v0 = *(const s16x8*)&src[s0 * SK + c8];
                    s16x8 v1 = *(const s16x8*)&src[s1 * SK + c8];
                    if (L0) {
#pragma unroll
                        for (int j = 0; j < 8; j++)
                            a[j] += bf2f((unsigned short)v0[j]) + bf2f((unsigned short)v1[j]);
                    } else {
#pragma unroll
                        for (int j = 0; j < 8; j++)
                            a[j] += (bf2f((unsigned short)v0[j]) * sc[j] + sh[j]) +
                                    (bf2f((unsigned short)v1[j]) * sc[j] + sh[j]);
                    }
                }
                if (k < hi) {
                    long long s0 = slots[k];
                    s16x8 v0 = *(const s16x8*)&src[s0 * SK + c8];
#pragma unroll
                    for (int j = 0; j < 8; j++) {
                        float f = bf2f((unsigned short)v0[j]);
                        a[j] += L0 ? f : (f * sc[j] + sh[j]);
                    }
                }
            }
            union { s16x8 v; unsigned short u[8]; } pk;
#pragma unroll
            for (int j = 0; j < 8; j++) pk.u[j] = f2bf(a[j]);
            *(s16x8*)&Xs[r * 128 + (c8 ^ ((r & 7) << 3))] = pk.v;
        }
    }

    // ---- weight fragments into registers ----
    int colbase = w * 32 + (lane & 15);
    s16x8 w1f[2][4], w2f[2][4];
#pragma unroll
    for (int cb = 0; cb < 2; cb++) {
        int col = colbase + cb * 16;
#pragma unroll
        for (int ks = 0; ks < KS1; ks++)
            w1f[cb][ks] = *(const s16x8*)&wt1[col * 128 + ks * 32 + (lane >> 4) * 8];
#pragma unroll
        for (int ks = 0; ks < 4; ks++)
            w2f[cb][ks] = *(const s16x8*)&wt2[col * 128 + ks * 32 + (lane >> 4) * 8];
    }
    float bs1[2], bs2[2];
#pragma unroll
    for (int cb = 0; cb < 2; cb++) {
        bs1[cb] = b1[colbase + cb * 16];
        bs2[cb] = b2[colbase + cb * 16];
    }

    __syncthreads();

    // ---- pass 1: T = relu(Xs @ W1 + b1) ----
    f32x4 acc[4][2];
#pragma unroll
    for (int rb = 0; rb < 4; rb++)
#pragma unroll
        for (int cb = 0; cb < 2; cb++) acc[rb][cb] = 0;
#pragma unroll
    for (int ks = 0; ks < KS1; ks++) {
        int lk = ks * 32 + (lane >> 4) * 8;
        s16x8 af[4];
#pragma unroll
        for (int rb = 0; rb < 4; rb++) {
            int r = rb * 16 + (lane & 15);
            af[rb] = *(const s16x8*)&Xs[r * 128 + (lk ^ ((r & 7) << 3))];
        }
#pragma unroll
        for (int rb = 0; rb < 4; rb++)
#pragma unroll
            for (int cb = 0; cb < 2; cb++)
                acc[rb][cb] = __builtin_amdgcn_mfma_f32_16x16x32_bf16(af[rb], w1f[cb][ks], acc[rb][cb], 0, 0, 0);
    }

    __syncthreads();    // all Xs reads done

    // write T into Xs (same swizzle)
#pragma unroll
    for (int rb = 0; rb < 4; rb++)
#pragma unroll
        for (int cb = 0; cb < 2; cb++) {
            int col = colbase + cb * 16;
#pragma unroll
            for (int reg = 0; reg < 4; reg++) {
                int row = rb * 16 + (lane >> 4) * 4 + reg;
                float v = fmaxf(acc[rb][cb][reg] + bs1[cb], 0.f);
                Xs[row * 128 + (col ^ ((row & 7) << 3))] = f2bf(v);
            }
        }

    __syncthreads();

    // ---- pass 2: H = relu(T @ W2 + b2) ----
#pragma unroll
    for (int rb = 0; rb < 4; rb++)
#pragma unroll
        for (int cb = 0; cb < 2; cb++) acc[rb][cb] = 0;
#pragma unroll
    for (int ks = 0; ks < 4; ks++) {
        int lk = ks * 32 + (lane >> 4) * 8;
        s16x8 af[4];
#pragma unroll
        for (int rb = 0; rb < 4; rb++) {
            int r = rb * 16 + (lane & 15);
            af[rb] = *(const s16x8*)&Xs[r * 128 + (lk ^ ((r & 7) << 3))];
        }
#pragma unroll
        for (int rb = 0; rb < 4; rb++)
#pragma unroll
            for (int cb = 0; cb < 2; cb++)
                acc[rb][cb] = __builtin_amdgcn_mfma_f32_16x16x32_bf16(af[rb], w2f[cb][ks], acc[rb][cb], 0, 0, 0);
    }

    // ---- epilogue: store h (bf16) + per-block BN partial sums ----
    float ps[2] = {0.f, 0.f}, pq[2] = {0.f, 0.f};
#pragma unroll
    for (int rb = 0; rb < 4; rb++)
#pragma unroll
        for (int cb = 0; cb < 2; cb++) {
            int col = colbase + cb * 16;
#pragma unroll
            for (int reg = 0; reg < 4; reg++) {
                long long row = rowBase + rb * 16 + (lane >> 4) * 4 + reg;
                float v = fmaxf(acc[rb][cb][reg] + bs2[cb], 0.f);
                unsigned short ub = f2bf(v);
                out[row * DD + col] = ub;
                float vb = bf2f(ub);
                ps[cb] += vb;
                pq[cb] += vb * vb;
            }
        }
#pragma unroll
    for (int cb = 0; cb < 2; cb++) {
        ps[cb] += __shfl_xor(ps[cb], 16); ps[cb] += __shfl_xor(ps[cb], 32);
        pq[cb] += __shfl_xor(pq[cb], 16); pq[cb] += __shfl_xor(pq[cb], 32);
        if (lane < 16) {
            int col = colbase + cb * 16;
            partials[(long long)blockIdx.x * 256 + col] = ps[cb];
            partials[(long long)blockIdx.x * 256 + 128 + col] = pq[cb];
        }
    }
}

// ---------- reduce BN partials ----------
__global__ void bn_red2_kernel(const float* __restrict__ partials, float* __restrict__ sums) {
    float s = 0.f;
    for (int b = blockIdx.x; b < NBLK; b += gridDim.x)
        s += partials[(long long)b * 256 + threadIdx.x];
    atomicAdd(&sums[threadIdx.x], s);
}

__global__ void bn_finalize_kernel(const float* __restrict__ sums,
                                   const float* __restrict__ gamma,
                                   const float* __restrict__ beta,
                                   float* __restrict__ ss) {
    int c = threadIdx.x;
    float mu = sums[c] / (float)NN;
    float var = sums[DD + c] / (float)NN - mu * mu;
    float sc = gamma[c] * rsqrtf(var + BN_EPS);
    ss[c] = sc;
    ss[DD + c] = beta[c] - mu * sc;
}

// ---------- per-graph max pool with on-the-fly BN affine ----------
__global__ void pool_kernel(const unsigned short* __restrict__ hm, const float* __restrict__ ss,
                            const int* __restrict__ start, float* __restrict__ pooled, int l) {
    int g = blockIdx.x;
    int c = threadIdx.x; // 128
    int lo = start[g], hi = start[g + 1];
    float sc = ss[c], sh = ss[DD + c];
    float m = -FLT_MAX;
    for (int n = lo; n < hi; n++)
        m = fmaxf(m, bf2f(hm[(long long)n * DD + c]) * sc + sh);
    pooled[(long long)g * (3 * DD) + l * DD + c] = m;
}

// ---------- final: out = relu(pooled @ w_emb + b_emb) ----------
__global__ __launch_bounds__(256) void emb_kernel(const float* __restrict__ pooled,
                                                  const float* __restrict__ w,
                                                  const float* __restrict__ b,
                                                  float* __restrict__ out) {
    __shared__ float pl[8][384];
    int tid = threadIdx.x;
    int g0 = blockIdx.x * 8;
#pragma unroll
    for (int i = 0; i < 12; i++) {
        int idx = tid + i * 256;
        int gg = idx / 384, c = idx % 384;
        pl[gg][c] = pooled[(long long)(g0 + gg) * 384 + c];
    }
    __syncthreads();
    float acc[8];
#pragma unroll
    for (int gg = 0; gg < 8; gg++) acc[gg] = 0.f;
    for (int k = 0; k < 384; k++) {
        float wv = w[k * 256 + tid];
#pragma unroll
        for (int gg = 0; gg < 8; gg++) acc[gg] += pl[gg][k] * wv;
    }
    float bb = b[tid];
#pragma unroll
    for (int gg = 0; gg < 8; gg++)
        out[(long long)(g0 + gg) * 256 + tid] = fmaxf(acc[gg] + bb, 0.f);
}

extern "C" void kernel_launch(void* const* d_in, const int* in_sizes, int n_in,
                              void* d_out, int out_size, void* d_ws, size_t ws_size,
                              hipStream_t stream) {
    const float* x = (const float*)d_in[0];
    const void* eidx = d_in[1];
    const void* batch = d_in[2];
    const float* w1[3] = { (const float*)d_in[3],  (const float*)d_in[9],  (const float*)d_in[15] };
    const float* b1[3] = { (const float*)d_in[4],  (const float*)d_in[10], (const float*)d_in[16] };
    const float* w2[3] = { (const float*)d_in[5],  (const float*)d_in[11], (const float*)d_in[17] };
    const float* b2[3] = { (const float*)d_in[6],  (const float*)d_in[12], (const float*)d_in[18] };
    const float* gm[3] = { (const float*)d_in[7],  (const float*)d_in[13], (const float*)d_in[19] };
    const float* bt[3] = { (const float*)d_in[8],  (const float*)d_in[14], (const float*)d_in[20] };
    const float* w_emb = (const float*)d_in[21];
    const float* b_emb = (const float*)d_in[22];
    float* out = (float*)d_out;

    // workspace: two ping-pong h buffers (R1 doubles as xb [N,96])
    unsigned short* R1 = (unsigned short*)d_ws;              // NN*128 u16
    unsigned short* R2 = R1 + (size_t)NN * DD;               // NN*128 u16
    float* pooled = (float*)(R2 + (size_t)NN * DD);          // NG*384
    float* partials = pooled + (size_t)NG * 384;             // NBLK*256
    unsigned short* wtb = (unsigned short*)(partials + (size_t)NBLK * 256); // 6*16384
    float* sums = (float*)(wtb + 6 * 16384);                 // 256
    float* ss = sums + 256;                                  // 256
    int* start = (int*)(ss + 256);                           // NG+1
    int* flags = start + NG + 1;                             // 2
    int* deg = flags + 2;                                    // NN
    int* incl = deg + NN;                                    // NN
    int* bsum = incl + NN;                                   // NB_SCAN
    int* rowptr = bsum + NB_SCAN;                            // NN+1
    int* cursor = rowptr + NN + 1;                           // NN
    int* slots = cursor + NN;                                // NE

    detect_kernel<<<1, 64, 0, stream>>>((const unsigned*)eidx, (const unsigned*)batch, flags);
    graph_starts_kernel<<<(NG + 1 + 255) / 256, 256, 0, stream>>>(batch, flags, start);

    // CSR build (once; edge_index is layer-invariant)
    hipMemsetAsync(deg, 0, (size_t)NN * sizeof(int), stream);
    count_kernel<<<(NE + 255) / 256, 256, 0, stream>>>(eidx, flags, deg);
    scan1_kernel<<<NB_SCAN, 256, 0, stream>>>(deg, incl, bsum);
    scan2_kernel<<<1, 1024, 0, stream>>>(bsum);
    scan3_kernel<<<NB_SCAN, 256, 0, stream>>>(incl, deg, bsum, rowptr, cursor);
    fill_kernel<<<(NE + 255) / 256, 256, 0, stream>>>(eidx, flags, cursor, slots);

    // x -> bf16 [N,96] into R1; weights -> bf16 transposed
    xconv_kernel<<<(NN * 12) / 256, 256, 0, stream>>>(x, R1);
    for (int l = 0; l < 3; l++)
        wconv_kernel<<<64, 256, 0, stream>>>(w1[l], w2[l], wtb + l * 2 * 16384,
                                             wtb + l * 2 * 16384 + 16384, (l == 0) ? FIN : DD);

    // layer 0: R1(xb) -> R2 ; layer 1: R2 -> R1 ; layer 2: R1 -> R2
    unsigned short* hin[3] = { R1, R2, R1 };
    unsigned short* hout[3] = { R2, R1, R2 };
    for (int l = 0; l < 3; l++) {
        const unsigned short* wt1 = wtb + l * 2 * 16384;
        const unsigned short* wt2 = wt1 + 16384;
        if (l == 0)
            fused_layer<1><<<NBLK, 256, 0, stream>>>(hin[l], ss, rowptr, slots, wt1, wt2,
                                                     b1[l], b2[l], hout[l], partials);
        else
            fused_layer<0><<<NBLK, 256, 0, stream>>>(hin[l], ss, rowptr, slots, wt1, wt2,
                                                     b1[l], b2[l], hout[l], partials);
        hipMemsetAsync(sums, 0, 256 * sizeof(float), stream);
        bn_red2_kernel<<<64, 256, 0, stream>>>(partials, sums);
        bn_finalize_kernel<<<1, 128, 0, stream>>>(sums, gm[l], bt[l], ss);
        pool_kernel<<<NG, 128, 0, stream>>>(hout[l], ss, start, pooled, l);
    }
    emb_kernel<<<NG / 8, 256, 0, stream>>>(pooled, w_emb, b_emb, out);
}